// Round 15
// baseline (398.370 us; speedup 1.0000x reference)
//
#include <hip/hip_runtime.h>
#include <hip/hip_bf16.h>
#include <stdint.h>

typedef float f32x16 __attribute__((ext_vector_type(16)));
typedef int   i32x4  __attribute__((ext_vector_type(4)));
typedef int   i32x8  __attribute__((ext_vector_type(8)));

#define LOG2E 1.4426950408889634f
#define WSCALE 16.0f

// fp8 MX operand layout (r10-r13 verified: absmax=0, conflicts=0):
// panel of R rows (R=128 A / 256 B) stored as
//   [k-tile t (64 k)][frag f (32 rows)][half h][lane l] x 16B
// chunk (f,h,l) holds row f*32+(l&31), k = t*64 + (l>>5)*32 + h*16 + 0..15.
// r15: one WAVE owns a 128x64 output tile (4 A-frags x 2 B-frags = 8
// MFMA/step, 12KB/step = 11.4 B/KFLOP vs r13's 15.6) — register-feasible
// (acc 128 + pipeline 96 ≈ 240 VGPR, no spill; r14's 128x128 spilled).
// Block = 4 waves spanning 128x256 (waves split N, share A via L1).
// Zero LDS / zero barriers (r13-verified null): fragments stream
// global->register via coalesced dwordx4; 2-deep register pipeline.
// W pre-scaled x16; epilogue multiplies logits by 1/16. MX scale = E8M0 1.0
// (byte 127) == exact fp8 matmul.

// ---------------- f32 -> OCP e4m3 (RNE, clamp; verified r8-r13 absmax=0) ----
__device__ __forceinline__ uint32_t f32_to_e4m3(float x) {
    uint32_t ux = __float_as_uint(x);
    uint32_t s = (ux >> 24) & 0x80u;
    float a = __uint_as_float(ux & 0x7FFFFFFFu);
    if (a >= 448.0f) return s | 0x7Eu;
    int e = (int)((ux >> 23) & 0xFFu) - 127;
    if (e < -6) {
        int n = __float2int_rn(a * 512.0f);
        return s | (uint32_t)n;
    }
    uint32_t m = ux & 0x7FFFFFu;
    uint32_t r = (m + 0x7FFFFu + ((m >> 20) & 1u)) >> 20;
    if (r == 8u) { r = 0u; e += 1; }
    if (e > 8 || (e == 8 && r == 7u)) return s | 0x7Eu;
    return s | ((uint32_t)(e + 7) << 3) | r;
}

__device__ __forceinline__ uint32_t pack4_fp8v(float4 v, float sc) {
    return f32_to_e4m3(v.x * sc) | (f32_to_e4m3(v.y * sc) << 8) |
           (f32_to_e4m3(v.z * sc) << 16) | (f32_to_e4m3(v.w * sc) << 24);
}

__device__ __forceinline__ uint32_t pack4_fp8(const float* s, float sc) {
    return f32_to_e4m3(s[0] * sc) | (f32_to_e4m3(s[1] * sc) << 8) |
           (f32_to_e4m3(s[2] * sc) << 16) | (f32_to_e4m3(s[3] * sc) << 24);
}

__device__ __forceinline__ uint4 cvt16_fp8(const float* s, float sc) {
    uint4 r;
    r.x = pack4_fp8(s, sc);      r.y = pack4_fp8(s + 4, sc);
    r.z = pack4_fp8(s + 8, sc);  r.w = pack4_fp8(s + 12, sc);
    return r;
}

// ---------------- prep: build indices from batch_sizes ----------------
__global__ void prep_kernel(const int* __restrict__ bs, int T,
                            const int* __restrict__ sentences,
                            int* __restrict__ hdr, float* __restrict__ fhdr,
                            int* __restrict__ row_ctx, int* __restrict__ row_tok) {
    __shared__ int off[1025];
    if (threadIdx.x == 0) {
        int acc = 0; off[0] = 0;
        for (int t = 0; t < T; ++t) { acc += bs[t]; off[t + 1] = acc; }
    }
    __syncthreads();
    const int total = off[T];
    const int Nf = total - off[1];
    const int Nb = total - off[2];
    for (int t = 1; t < T; ++t) {
        int start = off[t] - off[1];
        int cnt = off[t + 1] - off[t];
        for (int p = threadIdx.x; p < cnt; p += blockDim.x) {
            row_ctx[start + p] = off[t - 1] + p;
            row_tok[start + p] = sentences[off[t] + p];
        }
    }
    for (int i = 1; i < T - 1; ++i) {
        int start = Nf + off[i + 1] - off[2];
        int cnt = off[i + 2] - off[i + 1];
        for (int p = threadIdx.x; p < cnt; p += blockDim.x) {
            row_ctx[start + p] = off[i + 1] + p;
            row_tok[start + p] = sentences[off[i] + p];
        }
    }
    if (threadIdx.x == 0) {
        hdr[0] = Nf + Nb;
        hdr[1] = Nf;
        int bs0 = off[1];
        int bsl = off[T] - off[T - 1];
        fhdr[0] = (float)(2 * total - bs0 - bsl);
    }
}

// ---------------- W f32 -> fp8 (x16), MX panels, LDS-staged transpose -------
// (verified r10/r12: coalesced both sides)
__global__ void wconv_kernel(const float* __restrict__ W,
                             uint8_t* __restrict__ Wb, int K) {
    const int p = blockIdx.x >> 3, f = blockIdx.x & 7;
    __shared__ __align__(16) char tile[2048];
    char* panel = (char*)Wb + (size_t)p * ((size_t)K << 8);   // 256 rows * K B
    const int tid = threadIdx.x;
    const int rloc = tid >> 4;            // 0..31
    const int kloc = (tid & 15) << 2;     // 0..60, step 4
    const int h = (kloc >> 4) & 1;
    const int l = ((kloc >> 5) << 5) | rloc;
    const int ldst = h * 1024 + l * 16 + (kloc & 15);
    const float* src = W + (size_t)(p * 256 + f * 32 + rloc) * K + kloc;
    const int NT = K >> 6;
    for (int t = 0; t < NT; ++t) {
        const float4 v = *(const float4*)(src + t * 64);
        const uint32_t pk = pack4_fp8v(v, WSCALE);
        __syncthreads();                              // prev write-out done
        *(uint32_t*)(tile + ldst) = pk;
        __syncthreads();
        if (tid < 128)
            *(uint4*)(panel + (size_t)t * 16384 + f * 2048 + (tid << 4)) =
                *(const uint4*)(tile + (tid << 4));
    }
}

// ---------------- gather ctx rows -> fp8 128-row MX panels, zero S ----------
// (verified r10/r12)
__global__ void gather_kernel(const float* __restrict__ hs,
                              const int* __restrict__ row_ctx,
                              const int* __restrict__ hdr,
                              uint8_t* __restrict__ Hc,
                              float* __restrict__ S, int D2, int K) {
    const int p = blockIdx.x >> 2, f = blockIdx.x & 3;
    const int M = hdr[0], Nf = hdr[1];
    if (f == 0 && threadIdx.x < 128) S[p * 128 + threadIdx.x] = 0.f;
    char* panel = (char*)Hc + (size_t)p * ((size_t)K << 7);   // 128 rows * K B
    const int row0 = p * 128 + f * 32;
    const int nch = (K >> 6) << 7;
    for (int c = threadIdx.x; c < nch; c += 512) {
        const int t = c >> 7, h = (c >> 6) & 1, l = c & 63;
        const int row = row0 + (l & 31);
        char* d = panel + (size_t)t * 8192 + f * 2048 + h * 1024 + l * 16;
        if (row >= M) {
            uint4 z; z.x = z.y = z.z = z.w = 0u;
            *(uint4*)d = z;
        } else {
            const int ctx = row_ctx[row];
            const int k = t * 64 + ((l >> 5) << 5) + h * 16;
            *(uint4*)d = cvt16_fp8(hs + (size_t)ctx * D2 + (row < Nf ? 0 : K) + k, 1.0f);
        }
    }
}

// ---------------- main: 4-wave blocks, 128x64 per wave, zero-sync -----------
__global__ __launch_bounds__(256, 2)
void gemm_lse(const uint8_t* __restrict__ A,
              const uint8_t* __restrict__ B,
              const float* __restrict__ fb,
              const float* __restrict__ bb,
              float* __restrict__ S,
              const int* __restrict__ hdr, int K, int MT) {
    const int M = hdr[0], Nf = hdr[1];

    // XCD-aware bijective swizzle (m204), bm-fastest: consecutive blocks on
    // one XCD share the same B panel (L2-resident).
    const int nwg = gridDim.x, orig = blockIdx.x;
    const int q = nwg >> 3, rr = nwg & 7;
    const int xcd = orig & 7, i8 = orig >> 3;
    const int wgid = (xcd < rr ? xcd * (q + 1) : rr * (q + 1) + (xcd - rr) * q) + i8;
    const int bm = wgid % MT, bn = wgid / MT;
    if (bm * 128 >= M) return;

    const int lane = threadIdx.x & 63;
    const int wn = threadIdx.x >> 6;     // 4 waves split the 256-col N tile

    f32x16 acc[4][2];
#pragma unroll
    for (int i = 0; i < 4; ++i)
#pragma unroll
        for (int j = 0; j < 2; ++j) acc[i][j] = (f32x16)0.f;

    // fragment base pointers (fragment order == memory order)
    const char* pa = (const char*)A + (size_t)bm * ((size_t)K << 7)
                     + (lane << 4);                              // step 8192
    const char* pb = (const char*)B + (size_t)bn * ((size_t)K << 8)
                     + (wn << 12) + (lane << 4);                 // step 16384

    i32x4 x[12], y[12];   // A frags: [0..7] (2 per frag), B frags: [8..11]

#define LOADS(P, t) do {                                                      \
    const char* _a = pa + (size_t)(t) * 8192;                                 \
    const char* _b = pb + (size_t)(t) * 16384;                                \
    _Pragma("unroll")                                                         \
    for (int _f = 0; _f < 4; ++_f) {                                          \
        P[2 * _f]     = *(const i32x4*)(_a + _f * 2048);                      \
        P[2 * _f + 1] = *(const i32x4*)(_a + _f * 2048 + 1024);               \
    }                                                                         \
    _Pragma("unroll")                                                         \
    for (int _g = 0; _g < 2; ++_g) {                                          \
        P[8 + 2 * _g]     = *(const i32x4*)(_b + _g * 2048);                  \
        P[8 + 2 * _g + 1] = *(const i32x4*)(_b + _g * 2048 + 1024);           \
    }                                                                         \
} while (0)

#define CAT8(lo, hi) __builtin_shufflevector(lo, hi, 0, 1, 2, 3, 4, 5, 6, 7)

#define COMP(P) do {                                                          \
    _Pragma("unroll")                                                         \
    for (int _f = 0; _f < 4; ++_f) {                                          \
        const i32x8 _A = CAT8(P[2 * _f], P[2 * _f + 1]);                      \
        _Pragma("unroll")                                                     \
        for (int _g = 0; _g < 2; ++_g) {                                      \
            const i32x8 _B = CAT8(P[8 + 2 * _g], P[8 + 2 * _g + 1]);          \
            acc[_f][_g] = __builtin_amdgcn_mfma_scale_f32_32x32x64_f8f6f4(    \
                _A, _B, acc[_f][_g], 0, 0, 0, 127, 0, 127);                   \
        }                                                                     \
    }                                                                         \
} while (0)

    const int NT = K >> 6;   // 64-k steps (K=1024 -> 16)

    LOADS(x, 0);
    int t = 0;
    for (; t + 2 < NT; t += 2) {
        LOADS(y, t + 1);     // in flight while COMP(x)'s 8 MFMA run
        COMP(x);
        LOADS(x, t + 2);
        COMP(y);
    }
    if ((NT & 1) == 0) {     // t == NT-2
        LOADS(y, t + 1);
        COMP(x);
        COMP(y);
    } else {                 // t == NT-1
        COMP(x);
    }

    // epilogue: 32x32 C/D layout (m74/m101, verified r9-r13): col = lane&31,
    // row = (reg&3) + 8*(reg>>2) + 4*(lane>>5); frag (f,g) at rows f*32+...,
    // cols wn*64 + g*32 + ...
    const float k1 = LOG2E / WSCALE;
    const int v0 = bn * 256 + wn * 64 + (lane & 31);
    const float fbv0 = fb[v0] * LOG2E,      bbv0 = bb[v0] * LOG2E;
    const float fbv1 = fb[v0 + 32] * LOG2E, bbv1 = bb[v0 + 32] * LOG2E;
    const int mb0 = bm * 128 + ((lane >> 5) << 2);

#pragma unroll
    for (int f = 0; f < 4; ++f) {
#pragma unroll
        for (int reg = 0; reg < 16; ++reg) {
            const int m = mb0 + f * 32 + (reg & 3) + ((reg >> 2) << 3);
            if (m < M) {   // uniform across each 32-lane shuffle group
                const bool isf = m < Nf;
                float ps = exp2f(fmaf(acc[f][0][reg], k1, isf ? fbv0 : bbv0))
                         + exp2f(fmaf(acc[f][1][reg], k1, isf ? fbv1 : bbv1));
#pragma unroll
                for (int s = 1; s < 32; s <<= 1) ps += __shfl_xor(ps, s);
                if ((lane & 31) == 0) atomicAdd(&S[m], ps);
            }
        }
    }
#undef LOADS
#undef CAT8
#undef COMP
}

// ---------------- fallback (ws too small): naive exact f32 sum-exp ----------
__global__ void lse_naive(const float* __restrict__ hs,
                          const float* __restrict__ W,
                          const float* __restrict__ fb,
                          const float* __restrict__ bb,
                          const int* __restrict__ row_ctx,
                          const int* __restrict__ hdr,
                          float* __restrict__ S, int D2, int D, int V) {
    const int m = blockIdx.x;
    const int M = hdr[0], Nf = hdr[1];
    if (m >= M) return;
    __shared__ float hrow[2048];
    const int ctx = row_ctx[m];
    const float* h = hs + (size_t)ctx * D2 + (m < Nf ? 0 : D);
    for (int i = threadIdx.x; i < D; i += blockDim.x) hrow[i] = h[i];
    __syncthreads();
    const float* bias = (m < Nf) ? fb : bb;
    float ps = 0.f;
    for (int v = threadIdx.x; v < V; v += blockDim.x) {
        const float* w = W + (size_t)v * D;
        float dot = 0.f;
        for (int k = 0; k < D; ++k) dot = fmaf(hrow[k], w[k], dot);
        ps += exp2f((dot + bias[v]) * LOG2E);
    }
#pragma unroll
    for (int d = 1; d < 64; d <<= 1) ps += __shfl_xor(ps, d);
    __shared__ float wsum[4];
    const int wid = threadIdx.x >> 6, lane = threadIdx.x & 63;
    if (lane == 0) wsum[wid] = ps;
    __syncthreads();
    if (threadIdx.x == 0) S[m] = wsum[0] + wsum[1] + wsum[2] + wsum[3];
}

// ---------------- gold logits (exact f32) ----------------
__global__ void gold_kernel(const float* __restrict__ hs,
                            const float* __restrict__ W,
                            const float* __restrict__ fb,
                            const float* __restrict__ bb,
                            const int* __restrict__ row_ctx,
                            const int* __restrict__ row_tok,
                            const int* __restrict__ hdr,
                            float* __restrict__ goldv, int D2, int D) {
    const int m = blockIdx.x;
    const int M = hdr[0];
    if (m >= M) return;
    const int Nf = hdr[1];
    const int ctx = row_ctx[m], tok = row_tok[m];
    const float4* h = (const float4*)(hs + (size_t)ctx * D2 + (m < Nf ? 0 : D));
    const float4* w = (const float4*)(W + (size_t)tok * D);
    float s = 0.f;
    for (int i = threadIdx.x; i < D / 4; i += blockDim.x) {
        float4 a = h[i], b = w[i];
        s += a.x * b.x + a.y * b.y + a.z * b.z + a.w * b.w;
    }
#pragma unroll
    for (int d = 1; d < 64; d <<= 1) s += __shfl_xor(s, d);
    __shared__ float wsum[4];
    const int wid = threadIdx.x >> 6, lane = threadIdx.x & 63;
    if (lane == 0) wsum[wid] = s;
    __syncthreads();
    if (threadIdx.x == 0) {
        float tot = wsum[0] + wsum[1] + wsum[2] + wsum[3];
        tot += (m < Nf ? fb[tok] : bb[tok]);
        goldv[m] = tot;
    }
}

// ---------------- final reduce ----------------
__global__ void final_kernel(const float* __restrict__ S,
                             const float* __restrict__ goldv,
                             const int* __restrict__ hdr,
                             const float* __restrict__ fhdr,
                             float* __restrict__ out) {
    const int M = hdr[0];
    float s = 0.f;
    for (int m = threadIdx.x; m < M; m += blockDim.x)
        s += logf(S[m]) - goldv[m];
#pragma unroll
    for (int d = 1; d < 64; d <<= 1) s += __shfl_xor(s, d);
    __shared__ float wsum[4];
    const int wid = threadIdx.x >> 6, lane = threadIdx.x & 63;
    if (lane == 0) wsum[wid] = s;
    __syncthreads();
    if (threadIdx.x == 0)
        out[0] = (wsum[0] + wsum[1] + wsum[2] + wsum[3]) / fhdr[0];
}

extern "C" void kernel_launch(void* const* d_in, const int* in_sizes, int n_in,
                              void* d_out, int out_size, void* d_ws, size_t ws_size,
                              hipStream_t stream) {
    const float* hs  = (const float*)d_in[0];
    const float* W   = (const float*)d_in[1];
    const float* fb  = (const float*)d_in[2];
    const float* bb  = (const float*)d_in[3];
    const int* sent  = (const int*)d_in[4];
    const int* bs    = (const int*)d_in[5];
    const int total  = in_sizes[4];
    const int T      = in_sizes[5];
    const int V      = in_sizes[2];
    const int D      = in_sizes[1] / V;
    const int D2     = in_sizes[0] / total;
    const int Mcap   = ((2 * total) + 127) & ~127;   // 128-aligned upper bound
    const int MT     = Mcap / 128;
    const int NN     = V / 256;

    char* p = (char*)d_ws;
    int*   hdr     = (int*)p;            p += 256;
    float* fhdr    = (float*)p;          p += 256;
    int*   row_ctx = (int*)p;            p += (size_t)Mcap * 4;
    int*   row_tok = (int*)p;            p += (size_t)Mcap * 4;
    float* S       = (float*)p;          p += (size_t)Mcap * 4;
    float* goldv   = (float*)p;          p += (size_t)Mcap * 4;
    uint8_t* Hc    = (uint8_t*)p;        p += (size_t)Mcap * D;     // fp8
    uint8_t* Wb    = (uint8_t*)p;
    const size_t need_wb = (size_t)(p - (char*)d_ws) + (size_t)V * D;

    prep_kernel<<<1, 256, 0, stream>>>(bs, T, sent, hdr, fhdr, row_ctx, row_tok);

    if (ws_size >= need_wb) {
        gather_kernel<<<MT * 4, 512, 0, stream>>>(hs, row_ctx, hdr, Hc, S, D2, D);
        wconv_kernel<<<(V / 256) * 8, 512, 0, stream>>>(W, Wb, D);
        gemm_lse<<<NN * MT, 256, 0, stream>>>(Hc, Wb, fb, bb, S, hdr, D, MT);
    } else {
        lse_naive<<<Mcap, 256, 0, stream>>>(hs, W, fb, bb, row_ctx, hdr, S, D2, D, V);
    }

    gold_kernel<<<Mcap, 256, 0, stream>>>(hs, W, fb, bb, row_ctx, row_tok, hdr, goldv, D2, D);
    final_kernel<<<1, 256, 0, stream>>>(S, goldv, hdr, fhdr, (float*)d_out);
}

// Round 16
// 257.049 us; speedup vs baseline: 1.5498x; 1.5498x over previous
//
#include <hip/hip_runtime.h>
#include <hip/hip_bf16.h>
#include <stdint.h>

typedef float f32x16 __attribute__((ext_vector_type(16)));
typedef int   i32x4  __attribute__((ext_vector_type(4)));
typedef int   i32x8  __attribute__((ext_vector_type(8)));

#define LOG2E 1.4426950408889634f
#define WSCALE 16.0f

// fp8 MX operand layout (r10-r13 verified: absmax=0, conflicts=0):
// panel of R rows (R=128 A / 256 B) stored as
//   [k-tile t (64 k)][frag f (32 rows)][half h][lane l] x 16B
// chunk (f,h,l) holds row f*32+(l&31), k = t*64 + (l>>5)*32 + h*16 + 0..15.
// r16: r13's zero-sync streaming GEMM, but SINGLE-buffered operands so
// unified regs (arch + 64 AGPR acc) stay <= 128 -> 4 waves/SIMD (vs r13's
// ~2.5): latency hidden by wave-level TLP (m114), not registers.
// Aux work (wconv + gather + gold) fused into ONE BW-bound kernel.
// W pre-scaled x16; epilogue multiplies logits by 1/16. MX scale = E8M0 1.0
// (byte 127) == exact fp8 matmul.

// ---------------- f32 -> OCP e4m3 (RNE, clamp; verified r8-r15 absmax=0) ----
__device__ __forceinline__ uint32_t f32_to_e4m3(float x) {
    uint32_t ux = __float_as_uint(x);
    uint32_t s = (ux >> 24) & 0x80u;
    float a = __uint_as_float(ux & 0x7FFFFFFFu);
    if (a >= 448.0f) return s | 0x7Eu;
    int e = (int)((ux >> 23) & 0xFFu) - 127;
    if (e < -6) {
        int n = __float2int_rn(a * 512.0f);
        return s | (uint32_t)n;
    }
    uint32_t m = ux & 0x7FFFFFu;
    uint32_t r = (m + 0x7FFFFu + ((m >> 20) & 1u)) >> 20;
    if (r == 8u) { r = 0u; e += 1; }
    if (e > 8 || (e == 8 && r == 7u)) return s | 0x7Eu;
    return s | ((uint32_t)(e + 7) << 3) | r;
}

__device__ __forceinline__ uint32_t pack4_fp8v(float4 v, float sc) {
    return f32_to_e4m3(v.x * sc) | (f32_to_e4m3(v.y * sc) << 8) |
           (f32_to_e4m3(v.z * sc) << 16) | (f32_to_e4m3(v.w * sc) << 24);
}

__device__ __forceinline__ uint32_t pack4_fp8(const float* s, float sc) {
    return f32_to_e4m3(s[0] * sc) | (f32_to_e4m3(s[1] * sc) << 8) |
           (f32_to_e4m3(s[2] * sc) << 16) | (f32_to_e4m3(s[3] * sc) << 24);
}

__device__ __forceinline__ uint4 cvt16_fp8(const float* s, float sc) {
    uint4 r;
    r.x = pack4_fp8(s, sc);      r.y = pack4_fp8(s + 4, sc);
    r.z = pack4_fp8(s + 8, sc);  r.w = pack4_fp8(s + 12, sc);
    return r;
}

// ---------------- prep: build indices from batch_sizes ----------------
__global__ void prep_kernel(const int* __restrict__ bs, int T,
                            const int* __restrict__ sentences,
                            int* __restrict__ hdr, float* __restrict__ fhdr,
                            int* __restrict__ row_ctx, int* __restrict__ row_tok) {
    __shared__ int off[1025];
    if (threadIdx.x == 0) {
        int acc = 0; off[0] = 0;
        for (int t = 0; t < T; ++t) { acc += bs[t]; off[t + 1] = acc; }
    }
    __syncthreads();
    const int total = off[T];
    const int Nf = total - off[1];
    const int Nb = total - off[2];
    for (int t = 1; t < T; ++t) {
        int start = off[t] - off[1];
        int cnt = off[t + 1] - off[t];
        for (int p = threadIdx.x; p < cnt; p += blockDim.x) {
            row_ctx[start + p] = off[t - 1] + p;
            row_tok[start + p] = sentences[off[t] + p];
        }
    }
    for (int i = 1; i < T - 1; ++i) {
        int start = Nf + off[i + 1] - off[2];
        int cnt = off[i + 2] - off[i + 1];
        for (int p = threadIdx.x; p < cnt; p += blockDim.x) {
            row_ctx[start + p] = off[i + 1] + p;
            row_tok[start + p] = sentences[off[i] + p];
        }
    }
    if (threadIdx.x == 0) {
        hdr[0] = Nf + Nb;
        hdr[1] = Nf;
        int bs0 = off[1];
        int bsl = off[T] - off[T - 1];
        fhdr[0] = (float)(2 * total - bs0 - bsl);
    }
}

// ---------------- fused staging: wconv + gather + gold in one kernel --------
// grid = NWC + NGA + NGO blocks x 512 threads.
//   [0, NWC):        W f32 -> fp8(x16) MX panels (r10/r12-verified body)
//   [NWC, NWC+NGA):  gather ctx rows -> fp8 MX panels + zero S (verified)
//   [NWC+NGA, ...):  gold logits, one WAVE per row (exact f32)
__global__ void stage_all(const float* __restrict__ W,
                          const float* __restrict__ hs,
                          const int* __restrict__ row_ctx,
                          const int* __restrict__ row_tok,
                          const int* __restrict__ hdr,
                          const float* __restrict__ fb,
                          const float* __restrict__ bb,
                          uint8_t* __restrict__ Wb,
                          uint8_t* __restrict__ Hc,
                          float* __restrict__ S,
                          float* __restrict__ goldv,
                          int K, int D2, int NWC, int NGA) {
    const int bx = blockIdx.x;
    const int tid = threadIdx.x;
    if (bx < NWC) {
        // ---- wconv ----
        const int p = bx >> 3, f = bx & 7;
        __shared__ __align__(16) char tile[2048];
        char* panel = (char*)Wb + (size_t)p * ((size_t)K << 8);
        const int rloc = tid >> 4;
        const int kloc = (tid & 15) << 2;
        const int h = (kloc >> 4) & 1;
        const int l = ((kloc >> 5) << 5) | rloc;
        const int ldst = h * 1024 + l * 16 + (kloc & 15);
        const float* src = W + (size_t)(p * 256 + f * 32 + rloc) * K + kloc;
        const int NT = K >> 6;
        for (int t = 0; t < NT; ++t) {
            const float4 v = *(const float4*)(src + t * 64);
            const uint32_t pk = pack4_fp8v(v, WSCALE);
            __syncthreads();
            *(uint32_t*)(tile + ldst) = pk;
            __syncthreads();
            if (tid < 128)
                *(uint4*)(panel + (size_t)t * 16384 + f * 2048 + (tid << 4)) =
                    *(const uint4*)(tile + (tid << 4));
        }
        return;
    }
    const int M = hdr[0], Nf = hdr[1];
    if (bx < NWC + NGA) {
        // ---- gather ----
        const int bx2 = bx - NWC;
        const int p = bx2 >> 2, f = bx2 & 3;
        if (f == 0 && tid < 128) S[p * 128 + tid] = 0.f;
        char* panel = (char*)Hc + (size_t)p * ((size_t)K << 7);
        const int row0 = p * 128 + f * 32;
        const int nch = (K >> 6) << 7;
        for (int c = tid; c < nch; c += 512) {
            const int t = c >> 7, h = (c >> 6) & 1, l = c & 63;
            const int row = row0 + (l & 31);
            char* d = panel + (size_t)t * 8192 + f * 2048 + h * 1024 + l * 16;
            if (row >= M) {
                uint4 z; z.x = z.y = z.z = z.w = 0u;
                *(uint4*)d = z;
            } else {
                const int ctx = row_ctx[row];
                const int k = t * 64 + ((l >> 5) << 5) + h * 16;
                *(uint4*)d = cvt16_fp8(hs + (size_t)ctx * D2 + (row < Nf ? 0 : K) + k, 1.0f);
            }
        }
        return;
    }
    // ---- gold: one wave per row ----
    const int bx3 = bx - NWC - NGA;
    const int lane = tid & 63, wid = tid >> 6;
    const int m = (bx3 << 3) + wid;
    if (m >= M) return;
    const int ctx = row_ctx[m], tok = row_tok[m];
    const float4* h = (const float4*)(hs + (size_t)ctx * D2 + (m < Nf ? 0 : K));
    const float4* w = (const float4*)(W + (size_t)tok * K);
    float s = 0.f;
#pragma unroll
    for (int j = 0; j < 4; ++j) {
        const int i = lane + j * 64;
        float4 a = h[i], b = w[i];
        s += a.x * b.x + a.y * b.y + a.z * b.z + a.w * b.w;
    }
#pragma unroll
    for (int d = 1; d < 64; d <<= 1) s += __shfl_xor(s, d);
    if (lane == 0) goldv[m] = s + (m < Nf ? fb[tok] : bb[tok]);
}

// ---------------- main: 4-wave blocks, 64x64/wave, zero-sync, high-TLP ------
// Single-buffered operands: unified regs = ~60 arch + 64 AGPR <= 128 ->
// 4 waves/SIMD; inter-wave overlap hides L2 latency (m114).
__global__ __launch_bounds__(256, 4)
void gemm_lse(const uint8_t* __restrict__ A,
              const uint8_t* __restrict__ B,
              const float* __restrict__ fb,
              const float* __restrict__ bb,
              float* __restrict__ S,
              const int* __restrict__ hdr, int K, int MT) {
    const int M = hdr[0], Nf = hdr[1];

    // XCD-aware bijective swizzle (m204), bm-fastest (verified r2-r13).
    const int nwg = gridDim.x, orig = blockIdx.x;
    const int q = nwg >> 3, rr = nwg & 7;
    const int xcd = orig & 7, i8 = orig >> 3;
    const int wgid = (xcd < rr ? xcd * (q + 1) : rr * (q + 1) + (xcd - rr) * q) + i8;
    const int bm = wgid % MT, bn = wgid / MT;
    if (bm * 128 >= M) return;

    const int lane = threadIdx.x & 63, wid = threadIdx.x >> 6;
    const int wm = wid >> 1, wn = wid & 1;   // 2x2 waves, each 64x64 out

    f32x16 acc00 = (f32x16)0.f, acc01 = (f32x16)0.f;
    f32x16 acc10 = (f32x16)0.f, acc11 = (f32x16)0.f;

    // fragment base pointers (fragment order == memory order, verified r13)
    const char* pa = (const char*)A + (size_t)bm * ((size_t)K << 7)
                     + (wm << 12) + (lane << 4);            // step stride 8192
    const char* pb = (const char*)B + (size_t)(bn >> 1) * ((size_t)K << 8)
                     + ((bn & 1) << 13) + (wn << 12) + (lane << 4); // stride 16384

#define CAT8(lo, hi) __builtin_shufflevector(lo, hi, 0, 1, 2, 3, 4, 5, 6, 7)

    const int NT = K >> 6;   // 64-k steps (K=1024 -> 16)

    for (int t = 0; t < NT; ++t) {
        const char* _a = pa + (size_t)t * 8192;
        const char* _b = pb + (size_t)t * 16384;
        const i32x4 a0l = *(const i32x4*)(_a);
        const i32x4 a0h = *(const i32x4*)(_a + 1024);
        const i32x4 a1l = *(const i32x4*)(_a + 2048);
        const i32x4 a1h = *(const i32x4*)(_a + 3072);
        const i32x4 b0l = *(const i32x4*)(_b);
        const i32x4 b0h = *(const i32x4*)(_b + 1024);
        const i32x4 b1l = *(const i32x4*)(_b + 2048);
        const i32x4 b1h = *(const i32x4*)(_b + 3072);
        const i32x8 A0 = CAT8(a0l, a0h);
        const i32x8 A1 = CAT8(a1l, a1h);
        const i32x8 B0 = CAT8(b0l, b0h);
        const i32x8 B1 = CAT8(b1l, b1h);
        acc00 = __builtin_amdgcn_mfma_scale_f32_32x32x64_f8f6f4(
            A0, B0, acc00, 0, 0, 0, 127, 0, 127);
        acc01 = __builtin_amdgcn_mfma_scale_f32_32x32x64_f8f6f4(
            A0, B1, acc01, 0, 0, 0, 127, 0, 127);
        acc10 = __builtin_amdgcn_mfma_scale_f32_32x32x64_f8f6f4(
            A1, B0, acc10, 0, 0, 0, 127, 0, 127);
        acc11 = __builtin_amdgcn_mfma_scale_f32_32x32x64_f8f6f4(
            A1, B1, acc11, 0, 0, 0, 127, 0, 127);
    }

    // epilogue: 32x32 C/D layout (m74/m101, verified r9-r15): col = lane&31,
    // row = (reg&3) + 8*(reg>>2) + 4*(lane>>5).
    const float k1 = LOG2E / WSCALE;
    const int v0 = bn * 128 + wn * 64 + (lane & 31);
    const float fbv0 = fb[v0] * LOG2E,      bbv0 = bb[v0] * LOG2E;
    const float fbv1 = fb[v0 + 32] * LOG2E, bbv1 = bb[v0 + 32] * LOG2E;
    const int mb0 = bm * 128 + wm * 64 + ((lane >> 5) << 2);

#define EPI(T0, T1, MB) do {                                                  \
    _Pragma("unroll")                                                         \
    for (int reg = 0; reg < 16; ++reg) {                                      \
        const int m = (MB) + (reg & 3) + ((reg >> 2) << 3);                   \
        if (m < M) {   /* uniform across each 32-lane shuffle group */        \
            const bool isf = m < Nf;                                          \
            float ps = exp2f(fmaf(T0[reg], k1, isf ? fbv0 : bbv0))            \
                     + exp2f(fmaf(T1[reg], k1, isf ? fbv1 : bbv1));           \
            _Pragma("unroll")                                                 \
            for (int s = 1; s < 32; s <<= 1) ps += __shfl_xor(ps, s);         \
            if ((lane & 31) == 0) atomicAdd(&S[m], ps);                       \
        }                                                                     \
    }                                                                         \
} while (0)

    EPI(acc00, acc01, mb0);
    EPI(acc10, acc11, mb0 + 32);

#undef CAT8
#undef EPI
}

// ---------------- fallback (ws too small): naive exact f32 sum-exp ----------
__global__ void lse_naive(const float* __restrict__ hs,
                          const float* __restrict__ W,
                          const float* __restrict__ fb,
                          const float* __restrict__ bb,
                          const int* __restrict__ row_ctx,
                          const int* __restrict__ hdr,
                          float* __restrict__ S, int D2, int D, int V) {
    const int m = blockIdx.x;
    const int M = hdr[0], Nf = hdr[1];
    if (m >= M) return;
    __shared__ float hrow[2048];
    const int ctx = row_ctx[m];
    const float* h = hs + (size_t)ctx * D2 + (m < Nf ? 0 : D);
    for (int i = threadIdx.x; i < D; i += blockDim.x) hrow[i] = h[i];
    __syncthreads();
    const float* bias = (m < Nf) ? fb : bb;
    float ps = 0.f;
    for (int v = threadIdx.x; v < V; v += blockDim.x) {
        const float* w = W + (size_t)v * D;
        float dot = 0.f;
        for (int k = 0; k < D; ++k) dot = fmaf(hrow[k], w[k], dot);
        ps += exp2f((dot + bias[v]) * LOG2E);
    }
#pragma unroll
    for (int d = 1; d < 64; d <<= 1) ps += __shfl_xor(ps, d);
    __shared__ float wsum[4];
    const int wid = threadIdx.x >> 6, lane = threadIdx.x & 63;
    if (lane == 0) wsum[wid] = ps;
    __syncthreads();
    if (threadIdx.x == 0) S[m] = wsum[0] + wsum[1] + wsum[2] + wsum[3];
}

// ---------------- gold fallback (paired with lse_naive path) ----------------
__global__ void gold_kernel(const float* __restrict__ hs,
                            const float* __restrict__ W,
                            const float* __restrict__ fb,
                            const float* __restrict__ bb,
                            const int* __restrict__ row_ctx,
                            const int* __restrict__ row_tok,
                            const int* __restrict__ hdr,
                            float* __restrict__ goldv, int D2, int D) {
    const int m = blockIdx.x;
    const int M = hdr[0];
    if (m >= M) return;
    const int Nf = hdr[1];
    const int ctx = row_ctx[m], tok = row_tok[m];
    const float4* h = (const float4*)(hs + (size_t)ctx * D2 + (m < Nf ? 0 : D));
    const float4* w = (const float4*)(W + (size_t)tok * D);
    float s = 0.f;
    for (int i = threadIdx.x; i < D / 4; i += blockDim.x) {
        float4 a = h[i], b = w[i];
        s += a.x * b.x + a.y * b.y + a.z * b.z + a.w * b.w;
    }
#pragma unroll
    for (int d = 1; d < 64; d <<= 1) s += __shfl_xor(s, d);
    __shared__ float wsum[4];
    const int wid = threadIdx.x >> 6, lane = threadIdx.x & 63;
    if (lane == 0) wsum[wid] = s;
    __syncthreads();
    if (threadIdx.x == 0) {
        float tot = wsum[0] + wsum[1] + wsum[2] + wsum[3];
        tot += (m < Nf ? fb[tok] : bb[tok]);
        goldv[m] = tot;
    }
}

// ---------------- final reduce ----------------
__global__ void final_kernel(const float* __restrict__ S,
                             const float* __restrict__ goldv,
                             const int* __restrict__ hdr,
                             const float* __restrict__ fhdr,
                             float* __restrict__ out) {
    const int M = hdr[0];
    float s = 0.f;
    for (int m = threadIdx.x; m < M; m += blockDim.x)
        s += logf(S[m]) - goldv[m];
#pragma unroll
    for (int d = 1; d < 64; d <<= 1) s += __shfl_xor(s, d);
    __shared__ float wsum[4];
    const int wid = threadIdx.x >> 6, lane = threadIdx.x & 63;
    if (lane == 0) wsum[wid] = s;
    __syncthreads();
    if (threadIdx.x == 0)
        out[0] = (wsum[0] + wsum[1] + wsum[2] + wsum[3]) / fhdr[0];
}

extern "C" void kernel_launch(void* const* d_in, const int* in_sizes, int n_in,
                              void* d_out, int out_size, void* d_ws, size_t ws_size,
                              hipStream_t stream) {
    const float* hs  = (const float*)d_in[0];
    const float* W   = (const float*)d_in[1];
    const float* fb  = (const float*)d_in[2];
    const float* bb  = (const float*)d_in[3];
    const int* sent  = (const int*)d_in[4];
    const int* bs    = (const int*)d_in[5];
    const int total  = in_sizes[4];
    const int T      = in_sizes[5];
    const int V      = in_sizes[2];
    const int D      = in_sizes[1] / V;
    const int D2     = in_sizes[0] / total;
    const int Mcap   = ((2 * total) + 127) & ~127;   // 128-aligned upper bound
    const int MT     = Mcap / 128;
    const int NN2    = V / 128;

    char* p = (char*)d_ws;
    int*   hdr     = (int*)p;            p += 256;
    float* fhdr    = (float*)p;          p += 256;
    int*   row_ctx = (int*)p;            p += (size_t)Mcap * 4;
    int*   row_tok = (int*)p;            p += (size_t)Mcap * 4;
    float* S       = (float*)p;          p += (size_t)Mcap * 4;
    float* goldv   = (float*)p;          p += (size_t)Mcap * 4;
    uint8_t* Hc    = (uint8_t*)p;        p += (size_t)Mcap * D;     // fp8
    uint8_t* Wb    = (uint8_t*)p;
    const size_t need_wb = (size_t)(p - (char*)d_ws) + (size_t)V * D;

    prep_kernel<<<1, 256, 0, stream>>>(bs, T, sent, hdr, fhdr, row_ctx, row_tok);

    if (ws_size >= need_wb) {
        const int NWC = (V / 256) * 8;
        const int NGA = MT * 4;
        const int NGO = Mcap / 8;
        stage_all<<<NWC + NGA + NGO, 512, 0, stream>>>(
            W, hs, row_ctx, row_tok, hdr, fb, bb, Wb, Hc, S, goldv, D, D2, NWC, NGA);
        gemm_lse<<<NN2 * MT, 256, 0, stream>>>(Hc, Wb, fb, bb, S, hdr, D, MT);
    } else {
        lse_naive<<<Mcap, 256, 0, stream>>>(hs, W, fb, bb, row_ctx, hdr, S, D2, D, V);
        gold_kernel<<<Mcap, 256, 0, stream>>>(hs, W, fb, bb, row_ctx, row_tok, hdr, goldv, D2, D);
    }

    final_kernel<<<1, 256, 0, stream>>>(S, goldv, hdr, fhdr, (float*)d_out);
}